// Round 3
// baseline (462.445 us; speedup 1.0000x reference)
//
#include <hip/hip_runtime.h>
#include <math.h>

// Single fused kernel:
//  - every thread redundantly computes the 3x4 transform from the tiny
//    uniform inputs (~60 FLOPs, amortized over ~32 points/thread),
//  - grid-stride loop, unrolled x4 for 4 independent 16B loads in flight.
// Plain float4 loads/stores (same memory path as the verified baseline).
__global__ __launch_bounds__(256) void fused_apply(
    const float4* __restrict__ x,
    const float* __restrict__ rot_delta,
    const float* __restrict__ trans_delta,
    const float* __restrict__ scale,
    const float* __restrict__ Rin,
    const float* __restrict__ Tin,
    float4* __restrict__ out,
    int n)
{
    // ---- uniform transform computation (identical in every thread) ----
    const float th0 = rot_delta[0], th1 = rot_delta[1], th2 = rot_delta[2];
    const float r0 = trans_delta[0], r1 = trans_delta[1], r2 = trans_delta[2];

    const float angle = sqrtf(th0*th0 + th1*th1 + th2*th2);
    const bool small = angle < 1e-5f;
    const float a = small ? 1.0f : angle;
    const float s = sinf(a), c = cosf(a);
    const float A = small ? 1.0f        : s / a;
    const float B = small ? 0.5f        : (1.0f - c) / (a * a);
    const float C = small ? (1.0f/6.0f) : (a - s) / (a * a * a);

    // W = skew(theta)
    const float W[3][3] = {{0.0f, -th2,  th1},
                           { th2, 0.0f, -th0},
                           {-th1,  th0, 0.0f}};
    float W2[3][3];
    #pragma unroll
    for (int i = 0; i < 3; ++i)
        #pragma unroll
        for (int j = 0; j < 3; ++j)
            W2[i][j] = W[i][0]*W[0][j] + W[i][1]*W[1][j] + W[i][2]*W[2][j];

    float Rd[3][3], Vm[3][3];
    #pragma unroll
    for (int i = 0; i < 3; ++i)
        #pragma unroll
        for (int j = 0; j < 3; ++j) {
            const float I = (i == j) ? 1.0f : 0.0f;
            Rd[i][j] = I + A * W[i][j] + B * W2[i][j];
            Vm[i][j] = I + B * W[i][j] + C * W2[i][j];
        }

    const float dt0 = Vm[0][0]*r0 + Vm[0][1]*r1 + Vm[0][2]*r2;
    const float dt1 = Vm[1][0]*r0 + Vm[1][1]*r1 + Vm[1][2]*r2;
    const float dt2 = Vm[2][0]*r0 + Vm[2][1]*r1 + Vm[2][2]*r2;

    // M = [scale_col(Rd @ Rin) | T + dt], rows 0..2 (row 3 is 0,0,0,1)
    float m[3][4];
    #pragma unroll
    for (int i = 0; i < 3; ++i)
        #pragma unroll
        for (int j = 0; j < 3; ++j) {
            const float v = Rd[i][0]*Rin[0*3+j] + Rd[i][1]*Rin[1*3+j] + Rd[i][2]*Rin[2*3+j];
            m[i][j] = scale[j] * v;
        }
    m[0][3] = Tin[0] + dt0;
    m[1][3] = Tin[1] + dt1;
    m[2][3] = Tin[2] + dt2;

    const float m00 = m[0][0], m01 = m[0][1], m02 = m[0][2], m03 = m[0][3];
    const float m10 = m[1][0], m11 = m[1][1], m12 = m[1][2], m13 = m[1][3];
    const float m20 = m[2][0], m21 = m[2][1], m22 = m[2][2], m23 = m[2][3];

    // ---- streaming apply: grid-stride, unrolled x4 ----
    const int stride = (int)(gridDim.x * blockDim.x);
    int i = (int)(blockIdx.x * blockDim.x + threadIdx.x);

    for (; i + 3 * stride < n; i += 4 * stride) {
        const float4 v0 = x[i];
        const float4 v1 = x[i + stride];
        const float4 v2 = x[i + 2 * stride];
        const float4 v3 = x[i + 3 * stride];

        float4 o0, o1, o2, o3;
        o0.x = fmaf(m00, v0.x, fmaf(m01, v0.y, fmaf(m02, v0.z, m03 * v0.w)));
        o0.y = fmaf(m10, v0.x, fmaf(m11, v0.y, fmaf(m12, v0.z, m13 * v0.w)));
        o0.z = fmaf(m20, v0.x, fmaf(m21, v0.y, fmaf(m22, v0.z, m23 * v0.w)));
        o0.w = v0.w;
        o1.x = fmaf(m00, v1.x, fmaf(m01, v1.y, fmaf(m02, v1.z, m03 * v1.w)));
        o1.y = fmaf(m10, v1.x, fmaf(m11, v1.y, fmaf(m12, v1.z, m13 * v1.w)));
        o1.z = fmaf(m20, v1.x, fmaf(m21, v1.y, fmaf(m22, v1.z, m23 * v1.w)));
        o1.w = v1.w;
        o2.x = fmaf(m00, v2.x, fmaf(m01, v2.y, fmaf(m02, v2.z, m03 * v2.w)));
        o2.y = fmaf(m10, v2.x, fmaf(m11, v2.y, fmaf(m12, v2.z, m13 * v2.w)));
        o2.z = fmaf(m20, v2.x, fmaf(m21, v2.y, fmaf(m22, v2.z, m23 * v2.w)));
        o2.w = v2.w;
        o3.x = fmaf(m00, v3.x, fmaf(m01, v3.y, fmaf(m02, v3.z, m03 * v3.w)));
        o3.y = fmaf(m10, v3.x, fmaf(m11, v3.y, fmaf(m12, v3.z, m13 * v3.w)));
        o3.z = fmaf(m20, v3.x, fmaf(m21, v3.y, fmaf(m22, v3.z, m23 * v3.w)));
        o3.w = v3.w;

        out[i]              = o0;
        out[i + stride]     = o1;
        out[i + 2 * stride] = o2;
        out[i + 3 * stride] = o3;
    }
    for (; i < n; i += stride) {
        const float4 v = x[i];
        float4 o;
        o.x = fmaf(m00, v.x, fmaf(m01, v.y, fmaf(m02, v.z, m03 * v.w)));
        o.y = fmaf(m10, v.x, fmaf(m11, v.y, fmaf(m12, v.z, m13 * v.w)));
        o.z = fmaf(m20, v.x, fmaf(m21, v.y, fmaf(m22, v.z, m23 * v.w)));
        o.w = v.w;
        out[i] = o;
    }
}

extern "C" void kernel_launch(void* const* d_in, const int* in_sizes, int n_in,
                              void* d_out, int out_size, void* d_ws, size_t ws_size,
                              hipStream_t stream) {
    const float* x           = (const float*)d_in[0];
    const float* rot_delta   = (const float*)d_in[1];
    const float* trans_delta = (const float*)d_in[2];
    const float* scale       = (const float*)d_in[3];
    const float* R           = (const float*)d_in[4];
    const float* T           = (const float*)d_in[5];

    const int n = in_sizes[0] / 4;   // number of float4 points (in_sizes is in floats)
    const int block = 256;
    // Capped grid + grid-stride: 2048 blocks = 8 per CU on 256 CUs.
    int grid = (n + block - 1) / block;
    if (grid > 2048) grid = 2048;

    fused_apply<<<grid, block, 0, stream>>>((const float4*)x, rot_delta, trans_delta,
                                            scale, R, T, (float4*)d_out, n);
}